// Round 10
// baseline (777.572 us; speedup 1.0000x reference)
//
#include <hip/hip_runtime.h>
#include <stdint.h>
#include <math.h>

typedef unsigned short ushort_t;
typedef __attribute__((ext_vector_type(8))) short bf16x8;
typedef __attribute__((ext_vector_type(16))) float f32x16;

#define EPI_STRIDE 1032   // 258 f32 per LDS row (conflict-free epilogue)

__device__ __forceinline__ ushort_t f2bf(float f) {
  union { float f; unsigned u; } cv; cv.f = f;
  unsigned r = cv.u + 0x7fffu + ((cv.u >> 16) & 1u);
  return (ushort_t)(r >> 16);
}

__device__ __forceinline__ void gl_lds16(const void* g, void* l) {
  typedef __attribute__((address_space(1))) const char gchar;
  typedef __attribute__((address_space(3))) char lchar;
  __builtin_amdgcn_global_load_lds((gchar*)g, (lchar*)l, 16, 0, 0);
}

__device__ __forceinline__ f32x16 MFMA32(bf16x8 a, bf16x8 b, f32x16 c) {
  return __builtin_amdgcn_mfma_f32_32x32x16_bf16(a, b, c, 0, 0, 0);
}

// ---------------- LayerNorm (fp32 in) -> bf16 xn ----------------
__global__ __launch_bounds__(256) void ln_kernel(const float* __restrict__ x,
                                                 const float* __restrict__ gamma,
                                                 const float* __restrict__ beta,
                                                 ushort_t* __restrict__ xn) {
  const int row = blockIdx.x;
  const int t = threadIdx.x;
  const float4 v = ((const float4*)(x + (size_t)row * 1024))[t];
  float s  = v.x + v.y + v.z + v.w;
  float ss = v.x * v.x + v.y * v.y + v.z * v.z + v.w * v.w;
#pragma unroll
  for (int o = 32; o >= 1; o >>= 1) {
    s  += __shfl_xor(s, o);
    ss += __shfl_xor(ss, o);
  }
  __shared__ float red[10];
  const int wave = t >> 6, lane = t & 63;
  if (lane == 0) { red[wave] = s; red[4 + wave] = ss; }
  __syncthreads();
  if (t == 0) {
    float S  = red[0] + red[1] + red[2] + red[3];
    float SS = red[4] + red[5] + red[6] + red[7];
    float mu  = S * (1.0f / 1024.0f);
    float var = SS * (1.0f / 1024.0f) - mu * mu;
    red[8] = mu;
    red[9] = rsqrtf(var + 1e-5f);
  }
  __syncthreads();
  const float mu = red[8], rs = red[9];
  const float4 g = ((const float4*)gamma)[t];
  const float4 b = ((const float4*)beta)[t];
  ushort4 o;
  o.x = f2bf((v.x - mu) * rs * g.x + b.x);
  o.y = f2bf((v.y - mu) * rs * g.y + b.y);
  o.z = f2bf((v.z - mu) * rs * g.z + b.z);
  o.w = f2bf((v.w - mu) * rs * g.w + b.w);
  ((ushort4*)(xn + (size_t)row * 1024))[t] = o;
}

// ---------------- transpose + cast: in[e][R][C] fp32 -> out[e][C][R] bf16 ----------------
__global__ __launch_bounds__(256) void transpose_cast(const float* __restrict__ in,
                                                      ushort_t* __restrict__ out,
                                                      int R, int C) {
  __shared__ float tile[32][33];
  const int e = blockIdx.z;
  const float* src = in + (size_t)e * R * C;
  ushort_t* dst = out + (size_t)e * R * C;
  const int c0 = blockIdx.x * 32, r0 = blockIdx.y * 32;
  const int tx = threadIdx.x, ty = threadIdx.y;
#pragma unroll
  for (int j = 0; j < 32; j += 8)
    tile[ty + j][tx] = src[(size_t)(r0 + ty + j) * C + c0 + tx];
  __syncthreads();
#pragma unroll
  for (int j = 0; j < 32; j += 8)
    dst[(size_t)(c0 + ty + j) * R + r0 + tx] = f2bf(tile[tx][ty + j]);
}

// ====== 256x256 / BK=64 / ring-2, 4-wave 128x128, mfma 32x32x16, 1 barrier/slot ======
// Slot (64KB): A [256 rows][64 k] @0 (pitch 128B), B @32768. 16B granules.
// Swizzle: global granule g of row r lives at LDS granule g ^ (r&7).
// Stage: linear dest (wave*64+i*8 rows), inverse-swizzled source (l&7)^(l>>3).

template <int LDA_>
__device__ __forceinline__ void slot64(const char* arow, const char* brow,
                                       const ushort_t* sA0, const ushort_t* sB0,
                                       char* dstA, char* dstB, int kt, bool stg,
                                       int g0, int g1, int g2, int g3,
                                       f32x16 (&acc)[4][4]) {
  bf16x8 a0[4], a1[4], b0[4], b1[4];
  // ---- phase 1: k-steps 0,1 ----
#pragma unroll
  for (int i = 0; i < 4; i++) {
    a0[i] = *(const bf16x8*)(arow + i * 4096 + g0);
    a1[i] = *(const bf16x8*)(arow + i * 4096 + g1);
    b0[i] = *(const bf16x8*)(brow + i * 4096 + g0);
    b1[i] = *(const bf16x8*)(brow + i * 4096 + g1);
  }
  if (stg) {
#pragma unroll
    for (int i = 0; i < 8; i++)
      gl_lds16(sA0 + kt + (size_t)i * 8 * LDA_, dstA + i * 1024);
#pragma unroll
    for (int i = 0; i < 8; i++)
      gl_lds16(sB0 + kt + (size_t)i * 8 * LDA_, dstB + i * 1024);
  }
  __builtin_amdgcn_s_setprio(1);
#pragma unroll
  for (int mi = 0; mi < 4; mi++)
#pragma unroll
    for (int ni = 0; ni < 4; ni++)
      acc[mi][ni] = MFMA32(a0[mi], b0[ni], acc[mi][ni]);
#pragma unroll
  for (int mi = 0; mi < 4; mi++)
#pragma unroll
    for (int ni = 0; ni < 4; ni++)
      acc[mi][ni] = MFMA32(a1[mi], b1[ni], acc[mi][ni]);
  __builtin_amdgcn_s_setprio(0);
  // ---- phase 2: k-steps 2,3 (no barrier needed inside slot) ----
#pragma unroll
  for (int i = 0; i < 4; i++) {
    a0[i] = *(const bf16x8*)(arow + i * 4096 + g2);
    a1[i] = *(const bf16x8*)(arow + i * 4096 + g3);
    b0[i] = *(const bf16x8*)(brow + i * 4096 + g2);
    b1[i] = *(const bf16x8*)(brow + i * 4096 + g3);
  }
  __builtin_amdgcn_s_setprio(1);
#pragma unroll
  for (int mi = 0; mi < 4; mi++)
#pragma unroll
    for (int ni = 0; ni < 4; ni++)
      acc[mi][ni] = MFMA32(a0[mi], b0[ni], acc[mi][ni]);
#pragma unroll
  for (int mi = 0; mi < 4; mi++)
#pragma unroll
    for (int ni = 0; ni < 4; ni++)
      acc[mi][ni] = MFMA32(a1[mi], b1[ni], acc[mi][ni]);
  __builtin_amdgcn_s_setprio(0);
  // ---- slot close: next buffer landed; this buffer's reads all done ----
  asm volatile("s_waitcnt vmcnt(0)" ::: "memory");
  __builtin_amdgcn_s_barrier();
  asm volatile("" ::: "memory");
}

// EPI=0: H = gelu(A@B + bias), bf16. EPI=1: O = resid + A@B + bias, f32.
template <int EPI, int LDA, int LDC, int KTOT>
__global__ __launch_bounds__(256, 1) void gemm256(const ushort_t* __restrict__ A,
                                                  const ushort_t* __restrict__ Bw,
                                                  const float* __restrict__ bias,
                                                  const float* __restrict__ resid,
                                                  ushort_t* __restrict__ Hout,
                                                  float* __restrict__ Fout) {
  extern __shared__ char smem[];
  const int tid = threadIdx.x;
  const int wave = tid >> 6, lane = tid & 63;

  const int bid = blockIdx.x;
  const int c = bid & 7, l = bid >> 3;
  const int tm = c * 8 + (l & 7);
  const int tn = l >> 3;
  const int row0 = tm * 256;
  const int col0 = tn * 256;
  const int e = (row0 >> 9) & 7;

  const ushort_t* gA = A + (size_t)row0 * LDA;
  const ushort_t* gB = Bw + ((size_t)e * LDC + col0) * LDA;

  const int NT = KTOT / 64;   // even

  const int wm = wave >> 1, wn = wave & 1;
  const int l31 = lane & 31, kh = lane >> 5, l7 = lane & 7;

  // fragment read bases (swizzled): row pitch 128B, granule g at g^(row&7)
  const char* arow0 = smem + (wm * 128 + l31) * 128;
  const char* brow0 = smem + 32768 + (wn * 128 + l31) * 128;
  const char* arow1 = arow0 + 65536;
  const char* brow1 = brow0 + 65536;
  const int g0 = (((0 + kh) ^ l7) << 4);
  const int g1 = (((2 + kh) ^ l7) << 4);
  const int g2 = (((4 + kh) ^ l7) << 4);
  const int g3 = (((6 + kh) ^ l7) << 4);

  // staging: per-thread source base (inverse-swizzled), linear dest
  const ushort_t* sA0 = gA + (size_t)(wave * 64 + (lane >> 3)) * LDA + ((l7 ^ (lane >> 3)) * 8);
  const ushort_t* sB0 = gB + (size_t)(wave * 64 + (lane >> 3)) * LDA + ((l7 ^ (lane >> 3)) * 8);
  char* dstA0 = smem + wave * 8192;
  char* dstB0 = dstA0 + 32768;
  char* dstA1 = dstA0 + 65536;
  char* dstB1 = dstB0 + 65536;

  f32x16 acc[4][4] = {};

  // prologue: stage slot 0 into buf0
#pragma unroll
  for (int i = 0; i < 8; i++)
    gl_lds16(sA0 + (size_t)i * 8 * LDA, dstA0 + i * 1024);
#pragma unroll
  for (int i = 0; i < 8; i++)
    gl_lds16(sB0 + (size_t)i * 8 * LDA, dstB0 + i * 1024);
  asm volatile("s_waitcnt vmcnt(0)" ::: "memory");
  __builtin_amdgcn_s_barrier();
  asm volatile("" ::: "memory");

  for (int T = 0; T < NT; T += 2) {
    slot64<LDA>(arow0, brow0, sA0, sB0, dstA1, dstB1, (T + 1) * 64, true,
                g0, g1, g2, g3, acc);
    slot64<LDA>(arow1, brow1, sA0, sB0, dstA0, dstB0, (T + 2) * 64, (T + 2) < NT,
                g0, g1, g2, g3, acc);
  }

  // ---------------- LDS-gather epilogue: 8 rounds x 32 rows ----------------
  // C/D layout (32x32): col = lane&31, row = (reg&3) + 8*(reg>>2) + 4*kh
  float bv[4];
#pragma unroll
  for (int ni = 0; ni < 4; ni++)
    bv[ni] = bias[e * LDC + col0 + wn * 128 + ni * 32 + l31];

#pragma unroll
  for (int r = 0; r < 8; ++r) {
    if (wm == (r >> 2)) {
      const int mi = r & 3;
#pragma unroll
      for (int ni = 0; ni < 4; ++ni) {
        const int colb = (wn * 128 + ni * 32 + l31) * 4;
#pragma unroll
        for (int reg = 0; reg < 16; ++reg) {
          const int rowin = (reg & 3) + 8 * (reg >> 2) + 4 * kh;
          float v = acc[mi][ni][reg] + bv[ni];
          if (EPI == 0) {
            float v2 = v * v;
            float cc = fmaf(0.044715f, v2, 1.0f);
            float u  = exp2f(-2.3022078f * v * cc);
            v = __fdividef(v, 1.0f + u);
          }
          *(float*)(smem + (size_t)rowin * EPI_STRIDE + colb) = v;
        }
      }
    }
    __syncthreads();
    // read side: 32 rows x 256 cols, coalesced wide stores
#pragma unroll
    for (int i = 0; i < 8; ++i) {
      const int chunk = i * 256 + tid;       // 0..2047
      const int lr = chunk >> 6;             // 0..31
      const int cb = (chunk & 63) * 16;
      const float4 v4 = *(const float4*)(smem + (size_t)lr * EPI_STRIDE + cb);
      const int grow = row0 + r * 32 + lr;
      const int gcol = col0 + (chunk & 63) * 4;
      if (EPI == 0) {
        ushort4 o;
        o.x = f2bf(v4.x); o.y = f2bf(v4.y); o.z = f2bf(v4.z); o.w = f2bf(v4.w);
        *(ushort4*)(&Hout[(size_t)grow * LDC + gcol]) = o;
      } else {
        const float4 rs = *(const float4*)(&resid[(size_t)grow * LDC + gcol]);
        float4 o;
        o.x = v4.x + rs.x; o.y = v4.y + rs.y; o.z = v4.z + rs.z; o.w = v4.w + rs.w;
        *(float4*)(&Fout[(size_t)grow * LDC + gcol]) = o;
      }
    }
    __syncthreads();
  }
}

extern "C" void kernel_launch(void* const* d_in, const int* in_sizes, int n_in,
                              void* d_out, int out_size, void* d_ws, size_t ws_size,
                              hipStream_t stream) {
  const float* x     = (const float*)d_in[0];
  const float* gamma = (const float*)d_in[1];
  const float* beta  = (const float*)d_in[2];
  // d_in[3] = gate_w : logits discarded by the reference -> skip
  const float* w1    = (const float*)d_in[4];
  const float* b1    = (const float*)d_in[5];
  const float* w2    = (const float*)d_in[6];
  const float* b2    = (const float*)d_in[7];
  float* out = (float*)d_out;

  char* ws = (char*)d_ws;
  ushort_t* xn  = (ushort_t*)ws;                                   // 32MB
  ushort_t* w1t = (ushort_t*)(ws + 33554432);                      // 64MB
  ushort_t* w2t = (ushort_t*)(ws + 33554432 + 67108864);           // 64MB
  ushort_t* h   = (ushort_t*)(ws + 33554432 + 2 * 67108864);       // 128MB

  hipFuncSetAttribute(reinterpret_cast<const void*>(&gemm256<0, 1024, 4096, 1024>),
                      hipFuncAttributeMaxDynamicSharedMemorySize, 131072);
  hipFuncSetAttribute(reinterpret_cast<const void*>(&gemm256<1, 4096, 1024, 4096>),
                      hipFuncAttributeMaxDynamicSharedMemorySize, 131072);

  ln_kernel<<<16384, 256, 0, stream>>>(x, gamma, beta, xn);
  transpose_cast<<<dim3(128, 32, 8), dim3(32, 8), 0, stream>>>(w1, w1t, 1024, 4096);
  transpose_cast<<<dim3(32, 128, 8), dim3(32, 8), 0, stream>>>(w2, w2t, 4096, 1024);

  // GEMM1: M=16384 N=4096 K=1024 -> h = gelu(xn@w1 + b1)
  gemm256<0, 1024, 4096, 1024><<<dim3(1024), 256, 131072, stream>>>(xn, w1t, b1, nullptr, h, nullptr);
  // GEMM2: M=16384 N=1024 K=4096 -> out = x + h@w2 + b2
  gemm256<1, 4096, 1024, 4096><<<dim3(256), 256, 131072, stream>>>(h, w2t, b2, x, nullptr, out);
}

// Round 11
// 433.110 us; speedup vs baseline: 1.7953x; 1.7953x over previous
//
#include <hip/hip_runtime.h>
#include <stdint.h>
#include <math.h>

typedef unsigned short ushort_t;
typedef __attribute__((ext_vector_type(8))) short bf16x8;
typedef __attribute__((ext_vector_type(4))) float f32x4;

#define SLOT 24576        // 256x32 A (16KB) + 128x32 B (8KB)
#define EPI_STRIDE 520    // 130 f32 per LDS row (conflict-free epilogue)

#define DS_READ(D, B, O) asm volatile("ds_read_b128 %0, %1 offset:" O : "=v"(D) : "v"(B))
#define SCHED0 __builtin_amdgcn_sched_barrier(0)
#define BAR __builtin_amdgcn_s_barrier()
#define WAITL0 asm volatile("s_waitcnt lgkmcnt(0)" ::: "memory")

__device__ __forceinline__ ushort_t f2bf(float f) {
  union { float f; unsigned u; } cv; cv.f = f;
  unsigned r = cv.u + 0x7fffu + ((cv.u >> 16) & 1u);
  return (ushort_t)(r >> 16);
}

__device__ __forceinline__ void gl_lds16(const void* g, void* l) {
  typedef __attribute__((address_space(1))) const char gchar;
  typedef __attribute__((address_space(3))) char lchar;
  __builtin_amdgcn_global_load_lds((gchar*)g, (lchar*)l, 16, 0, 0);
}

__device__ __forceinline__ unsigned lds_addr(void* p) {
  typedef __attribute__((address_space(3))) char lchar;
  return (unsigned)(unsigned long long)(lchar*)p;
}

__device__ __forceinline__ f32x4 MFMA(bf16x8 a, bf16x8 b, f32x4 c) {
  return __builtin_amdgcn_mfma_f32_16x16x32_bf16(a, b, c, 0, 0, 0);
}

// ---------------- LayerNorm (fp32 in) -> bf16 xn ----------------
__global__ __launch_bounds__(256) void ln_kernel(const float* __restrict__ x,
                                                 const float* __restrict__ gamma,
                                                 const float* __restrict__ beta,
                                                 ushort_t* __restrict__ xn) {
  const int row = blockIdx.x;
  const int t = threadIdx.x;
  const float4 v = ((const float4*)(x + (size_t)row * 1024))[t];
  float s  = v.x + v.y + v.z + v.w;
  float ss = v.x * v.x + v.y * v.y + v.z * v.z + v.w * v.w;
#pragma unroll
  for (int o = 32; o >= 1; o >>= 1) {
    s  += __shfl_xor(s, o);
    ss += __shfl_xor(ss, o);
  }
  __shared__ float red[10];
  const int wave = t >> 6, lane = t & 63;
  if (lane == 0) { red[wave] = s; red[4 + wave] = ss; }
  __syncthreads();
  if (t == 0) {
    float S  = red[0] + red[1] + red[2] + red[3];
    float SS = red[4] + red[5] + red[6] + red[7];
    float mu  = S * (1.0f / 1024.0f);
    float var = SS * (1.0f / 1024.0f) - mu * mu;
    red[8] = mu;
    red[9] = rsqrtf(var + 1e-5f);
  }
  __syncthreads();
  const float mu = red[8], rs = red[9];
  const float4 g = ((const float4*)gamma)[t];
  const float4 b = ((const float4*)beta)[t];
  ushort4 o;
  o.x = f2bf((v.x - mu) * rs * g.x + b.x);
  o.y = f2bf((v.y - mu) * rs * g.y + b.y);
  o.z = f2bf((v.z - mu) * rs * g.z + b.z);
  o.w = f2bf((v.w - mu) * rs * g.w + b.w);
  ((ushort4*)(xn + (size_t)row * 1024))[t] = o;
}

// ---------------- transpose + cast: in[e][R][C] fp32 -> out[e][C][R] bf16 ----------------
__global__ __launch_bounds__(256) void transpose_cast(const float* __restrict__ in,
                                                      ushort_t* __restrict__ out,
                                                      int R, int C) {
  __shared__ float tile[32][33];
  const int e = blockIdx.z;
  const float* src = in + (size_t)e * R * C;
  ushort_t* dst = out + (size_t)e * R * C;
  const int c0 = blockIdx.x * 32, r0 = blockIdx.y * 32;
  const int tx = threadIdx.x, ty = threadIdx.y;
#pragma unroll
  for (int j = 0; j < 32; j += 8)
    tile[ty + j][tx] = src[(size_t)(r0 + ty + j) * C + c0 + tx];
  __syncthreads();
#pragma unroll
  for (int j = 0; j < 32; j += 8)
    dst[(size_t)(c0 + ty + j) * R + r0 + tx] = f2bf(tile[tx][ty + j]);
}

// ======== 256x128 / BK=32 / ring-2, 4-wave block, 2 blocks/CU GEMM ========
// Slot (24KB): A rows 0-255 @0 (two 8KB halves), B rows 0-127 @16384. Rows = 64B.
// Swizzle: global granule g of row r lives at LDS granule g ^ ((r>>1)&3).
// 2 co-resident blocks per CU provide cross-block overlap of stalls (m97/m114).

template <int BASE>
__device__ __forceinline__ void mfma16(const bf16x8& a0, const bf16x8& a1,
                                       const bf16x8& a2, const bf16x8& a3,
                                       const bf16x8& b0, const bf16x8& b1,
                                       const bf16x8& b2, const bf16x8& b3,
                                       f32x4 (&acc)[8][4]) {
  __builtin_amdgcn_s_setprio(1);
  acc[BASE+0][0] = MFMA(a0, b0, acc[BASE+0][0]);
  acc[BASE+0][1] = MFMA(a0, b1, acc[BASE+0][1]);
  acc[BASE+0][2] = MFMA(a0, b2, acc[BASE+0][2]);
  acc[BASE+0][3] = MFMA(a0, b3, acc[BASE+0][3]);
  acc[BASE+1][0] = MFMA(a1, b0, acc[BASE+1][0]);
  acc[BASE+1][1] = MFMA(a1, b1, acc[BASE+1][1]);
  acc[BASE+1][2] = MFMA(a1, b2, acc[BASE+1][2]);
  acc[BASE+1][3] = MFMA(a1, b3, acc[BASE+1][3]);
  acc[BASE+2][0] = MFMA(a2, b0, acc[BASE+2][0]);
  acc[BASE+2][1] = MFMA(a2, b1, acc[BASE+2][1]);
  acc[BASE+2][2] = MFMA(a2, b2, acc[BASE+2][2]);
  acc[BASE+2][3] = MFMA(a2, b3, acc[BASE+2][3]);
  acc[BASE+3][0] = MFMA(a3, b0, acc[BASE+3][0]);
  acc[BASE+3][1] = MFMA(a3, b1, acc[BASE+3][1]);
  acc[BASE+3][2] = MFMA(a3, b2, acc[BASE+3][2]);
  acc[BASE+3][3] = MFMA(a3, b3, acc[BASE+3][3]);
  __builtin_amdgcn_s_setprio(0);
}

// One K32 slot: {asm-read frags from buf BUF; stage slot kt/32 into buf BUF^1;
//  lgkm0 -> 16 MFMA; read a4-7; lgkm0 -> 16 MFMA; vmcnt(0); barrier}
template <int BUF, bool STG, int LDA>
__device__ __forceinline__ void slot_body(unsigned aBase, unsigned bBase, char* smem,
                                          const ushort_t* gA, const ushort_t* gB,
                                          size_t sOff, int kt, int tid,
                                          f32x4 (&acc)[8][4]) {
  const unsigned sA = aBase + BUF * SLOT;
  const unsigned sB = bBase + BUF * SLOT;
  char* nb = smem + (BUF ^ 1) * SLOT;
  const int wdst = (tid >> 6) * 1024;
  bf16x8 a0, a1, a2, a3, b0, b1, b2, b3;
  DS_READ(b0, sB, "0");    DS_READ(b1, sB, "1024");
  DS_READ(b2, sB, "2048"); DS_READ(b3, sB, "3072");
  DS_READ(a0, sA, "0");    DS_READ(a1, sA, "1024");
  DS_READ(a2, sA, "2048"); DS_READ(a3, sA, "3072");
  if (STG) {
    gl_lds16(gA + sOff + kt,                     nb + wdst);
    gl_lds16(gA + (size_t)64  * LDA + sOff + kt, nb + 4096  + wdst);
    gl_lds16(gA + (size_t)128 * LDA + sOff + kt, nb + 8192  + wdst);
    gl_lds16(gA + (size_t)192 * LDA + sOff + kt, nb + 12288 + wdst);
    gl_lds16(gB + sOff + kt,                     nb + 16384 + wdst);
    gl_lds16(gB + (size_t)64  * LDA + sOff + kt, nb + 20480 + wdst);
  }
  SCHED0;
  WAITL0;
  SCHED0;
  mfma16<0>(a0, a1, a2, a3, b0, b1, b2, b3, acc);
  SCHED0;
  DS_READ(a0, sA, "4096"); DS_READ(a1, sA, "5120");
  DS_READ(a2, sA, "6144"); DS_READ(a3, sA, "7168");
  SCHED0;
  WAITL0;
  SCHED0;
  mfma16<4>(a0, a1, a2, a3, b0, b1, b2, b3, acc);
  SCHED0;
  if (STG) asm volatile("s_waitcnt vmcnt(0)" ::: "memory");
  BAR;
  SCHED0;
}

// EPI=0: H = gelu(A@B + bias), bf16. EPI=1: O = resid + A@B + bias, f32.
template <int EPI, int LDA, int LDC, int KTOT>
__global__ __launch_bounds__(256, 2) void gemmk(const ushort_t* __restrict__ A,
                                                const ushort_t* __restrict__ Bw,
                                                const float* __restrict__ bias,
                                                const float* __restrict__ resid,
                                                ushort_t* __restrict__ Hout,
                                                float* __restrict__ Fout) {
  extern __shared__ char smem[];
  const int tid = threadIdx.x;
  const int wave = tid >> 6, lane = tid & 63;

  // XCD-aware bijective swizzle (nwg % 8 == 0)
  const int bid = blockIdx.x;
  const int c = bid & 7, l = bid >> 3;
  const int tm = c * 8 + (l & 7);          // 0..63
  const int tn = l >> 3;
  const int row0 = tm * 256;
  const int col0 = tn * 128;
  const int e = (tm >> 1) & 7;

  const ushort_t* gA = A + (size_t)row0 * LDA;
  const ushort_t* gB = Bw + ((size_t)e * LDC + col0) * LDA;

  const int NT = KTOT / 32;   // 32 or 128 (even)

  const int wm = wave >> 1, wn = wave & 1;
  const int l15 = lane & 15, g = lane >> 4;
  const int sw = ((g ^ ((lane >> 1) & 3)) << 4);
  const int a_off = wm * 8192 + l15 * 64 + sw;
  const int b_off = 16384 + (wn * 64 + l15) * 64 + sw;
  const unsigned aBase = lds_addr(smem) + a_off;
  const unsigned bBase = lds_addr(smem) + b_off;

  // staging: thread covers row tid>>2 (of each 64-row quarter), inverse-swizzled granule
  const int gs = (tid & 3) ^ ((tid >> 3) & 3);
  const size_t sOff = (size_t)(tid >> 2) * LDA + gs * 8;

  f32x4 acc[8][4] = {};

  // prologue: stage slot 0 -> buf0
  {
    char* nb = smem;
    const int wdst = (tid >> 6) * 1024;
    gl_lds16(gA + sOff,                     nb + wdst);
    gl_lds16(gA + (size_t)64  * LDA + sOff, nb + 4096  + wdst);
    gl_lds16(gA + (size_t)128 * LDA + sOff, nb + 8192  + wdst);
    gl_lds16(gA + (size_t)192 * LDA + sOff, nb + 12288 + wdst);
    gl_lds16(gB + sOff,                     nb + 16384 + wdst);
    gl_lds16(gB + (size_t)64  * LDA + sOff, nb + 20480 + wdst);
  }
  asm volatile("s_waitcnt vmcnt(0)" ::: "memory");
  BAR;
  SCHED0;

#pragma unroll 1
  for (int T = 0; T + 2 < NT; T += 2) {
    slot_body<0, true, LDA>(aBase, bBase, smem, gA, gB, sOff, (T + 1) * 32, tid, acc);
    slot_body<1, true, LDA>(aBase, bBase, smem, gA, gB, sOff, (T + 2) * 32, tid, acc);
  }
  slot_body<0, true,  LDA>(aBase, bBase, smem, gA, gB, sOff, (NT - 1) * 32, tid, acc);
  slot_body<1, false, LDA>(aBase, bBase, smem, gA, gB, sOff, 0, tid, acc);

  // ---------------- LDS-gather epilogue: 4 rounds x 64 rows x 128 cols ----------------
  __syncthreads();

  float bv[4];
#pragma unroll
  for (int ni = 0; ni < 4; ni++)
    bv[ni] = bias[e * LDC + col0 + wn * 64 + ni * 16 + l15];

#pragma unroll
  for (int r = 0; r < 4; ++r) {
#pragma unroll
    for (int mh = 0; mh < 2; ++mh) {
      const int mi = 2 * r + mh;
      const int lrow = wm * 32 + mh * 16 + g * 4;
#pragma unroll
      for (int ni = 0; ni < 4; ++ni) {
        const int colb = (wn * 64 + ni * 16 + l15) * 4;
#pragma unroll
        for (int rr = 0; rr < 4; ++rr) {
          float v = acc[mi][ni][rr] + bv[ni];
          if (EPI == 0) {
            float v2 = v * v;
            float cc = fmaf(0.044715f, v2, 1.0f);
            float u  = exp2f(-2.3022078f * v * cc);
            v = __fdividef(v, 1.0f + u);
          }
          *(float*)(smem + (size_t)(lrow + rr) * EPI_STRIDE + colb) = v;
        }
      }
    }
    __syncthreads();
    // read side: 64 rows x 128 cols, coalesced wide stores
#pragma unroll
    for (int i = 0; i < 8; ++i) {
      const int chunk = i * 256 + tid;     // 0..2047
      const int lr = chunk >> 5;           // 0..63
      const int cb = (chunk & 31) * 16;
      const float4 v4 = *(const float4*)(smem + (size_t)lr * EPI_STRIDE + cb);
      const int grow = row0 + (lr < 32 ? r * 32 + lr : 128 + r * 32 + (lr - 32));
      const int gcol = col0 + (chunk & 31) * 4;
      if (EPI == 0) {
        ushort4 o;
        o.x = f2bf(v4.x); o.y = f2bf(v4.y); o.z = f2bf(v4.z); o.w = f2bf(v4.w);
        *(ushort4*)(&Hout[(size_t)grow * LDC + gcol]) = o;
      } else {
        const float4 rs = *(const float4*)(&resid[(size_t)grow * LDC + gcol]);
        float4 o;
        o.x = v4.x + rs.x; o.y = v4.y + rs.y; o.z = v4.z + rs.z; o.w = v4.w + rs.w;
        *(float4*)(&Fout[(size_t)grow * LDC + gcol]) = o;
      }
    }
    __syncthreads();
  }
}

extern "C" void kernel_launch(void* const* d_in, const int* in_sizes, int n_in,
                              void* d_out, int out_size, void* d_ws, size_t ws_size,
                              hipStream_t stream) {
  const float* x     = (const float*)d_in[0];
  const float* gamma = (const float*)d_in[1];
  const float* beta  = (const float*)d_in[2];
  // d_in[3] = gate_w : logits discarded by the reference -> skip
  const float* w1    = (const float*)d_in[4];
  const float* b1    = (const float*)d_in[5];
  const float* w2    = (const float*)d_in[6];
  const float* b2    = (const float*)d_in[7];
  float* out = (float*)d_out;

  char* ws = (char*)d_ws;
  ushort_t* xn  = (ushort_t*)ws;                                   // 32MB
  ushort_t* w1t = (ushort_t*)(ws + 33554432);                      // 64MB
  ushort_t* w2t = (ushort_t*)(ws + 33554432 + 67108864);           // 64MB
  ushort_t* h   = (ushort_t*)(ws + 33554432 + 2 * 67108864);       // 128MB

  hipFuncSetAttribute(reinterpret_cast<const void*>(&gemmk<0, 1024, 4096, 1024>),
                      hipFuncAttributeMaxDynamicSharedMemorySize, 49152);
  hipFuncSetAttribute(reinterpret_cast<const void*>(&gemmk<1, 4096, 1024, 4096>),
                      hipFuncAttributeMaxDynamicSharedMemorySize, 49152);

  ln_kernel<<<16384, 256, 0, stream>>>(x, gamma, beta, xn);
  transpose_cast<<<dim3(128, 32, 8), dim3(32, 8), 0, stream>>>(w1, w1t, 1024, 4096);
  transpose_cast<<<dim3(32, 128, 8), dim3(32, 8), 0, stream>>>(w2, w2t, 4096, 1024);

  // GEMM1: M=16384 N=4096 K=1024 -> h = gelu(xn@w1 + b1); 64 m x 32 n tiles
  gemmk<0, 1024, 4096, 1024><<<dim3(2048), 256, 49152, stream>>>(xn, w1t, b1, nullptr, h, nullptr);
  // GEMM2: M=16384 N=1024 K=4096 -> out = x + h@w2 + b2; 64 m x 8 n tiles
  gemmk<1, 4096, 1024, 4096><<<dim3(512), 256, 49152, stream>>>(h, w2t, b2, x, nullptr, out);
}

// Round 12
// 431.047 us; speedup vs baseline: 1.8039x; 1.0048x over previous
//
#include <hip/hip_runtime.h>
#include <stdint.h>
#include <math.h>

typedef unsigned short ushort_t;
typedef __attribute__((ext_vector_type(8))) short bf16x8;
typedef __attribute__((ext_vector_type(4))) float f32x4;

#define EPI_STRIDE 1032   // 258 f32 per LDS row (conflict-free epilogue)

#define DS_READ(D, B, O) asm volatile("ds_read_b128 %0, %1 offset:" O : "=v"(D) : "v"(B))
#define SCHED0 __builtin_amdgcn_sched_barrier(0)
#define BAR __builtin_amdgcn_s_barrier()
#define WAITL0 asm volatile("s_waitcnt lgkmcnt(0)" ::: "memory")
#define WAITV0 asm volatile("s_waitcnt vmcnt(0)" ::: "memory")

__device__ __forceinline__ ushort_t f2bf(float f) {
  union { float f; unsigned u; } cv; cv.f = f;
  unsigned r = cv.u + 0x7fffu + ((cv.u >> 16) & 1u);
  return (ushort_t)(r >> 16);
}

__device__ __forceinline__ void gl_lds16(const void* g, void* l) {
  typedef __attribute__((address_space(1))) const char gchar;
  typedef __attribute__((address_space(3))) char lchar;
  __builtin_amdgcn_global_load_lds((gchar*)g, (lchar*)l, 16, 0, 0);
}

__device__ __forceinline__ unsigned lds_addr(void* p) {
  typedef __attribute__((address_space(3))) char lchar;
  return (unsigned)(unsigned long long)(lchar*)p;
}

__device__ __forceinline__ f32x4 MFMA(bf16x8 a, bf16x8 b, f32x4 c) {
  return __builtin_amdgcn_mfma_f32_16x16x32_bf16(a, b, c, 0, 0, 0);
}

// ---------------- LayerNorm (fp32 in) -> bf16 xn ----------------
__global__ __launch_bounds__(256) void ln_kernel(const float* __restrict__ x,
                                                 const float* __restrict__ gamma,
                                                 const float* __restrict__ beta,
                                                 ushort_t* __restrict__ xn) {
  const int row = blockIdx.x;
  const int t = threadIdx.x;
  const float4 v = ((const float4*)(x + (size_t)row * 1024))[t];
  float s  = v.x + v.y + v.z + v.w;
  float ss = v.x * v.x + v.y * v.y + v.z * v.z + v.w * v.w;
#pragma unroll
  for (int o = 32; o >= 1; o >>= 1) {
    s  += __shfl_xor(s, o);
    ss += __shfl_xor(ss, o);
  }
  __shared__ float red[10];
  const int wave = t >> 6, lane = t & 63;
  if (lane == 0) { red[wave] = s; red[4 + wave] = ss; }
  __syncthreads();
  if (t == 0) {
    float S  = red[0] + red[1] + red[2] + red[3];
    float SS = red[4] + red[5] + red[6] + red[7];
    float mu  = S * (1.0f / 1024.0f);
    float var = SS * (1.0f / 1024.0f) - mu * mu;
    red[8] = mu;
    red[9] = rsqrtf(var + 1e-5f);
  }
  __syncthreads();
  const float mu = red[8], rs = red[9];
  const float4 g = ((const float4*)gamma)[t];
  const float4 b = ((const float4*)beta)[t];
  ushort4 o;
  o.x = f2bf((v.x - mu) * rs * g.x + b.x);
  o.y = f2bf((v.y - mu) * rs * g.y + b.y);
  o.z = f2bf((v.z - mu) * rs * g.z + b.z);
  o.w = f2bf((v.w - mu) * rs * g.w + b.w);
  ((ushort4*)(xn + (size_t)row * 1024))[t] = o;
}

// ---------------- transpose + cast: in[e][R][C] fp32 -> out[e][C][R] bf16 ----------------
__global__ __launch_bounds__(256) void transpose_cast(const float* __restrict__ in,
                                                      ushort_t* __restrict__ out,
                                                      int R, int C) {
  __shared__ float tile[32][33];
  const int e = blockIdx.z;
  const float* src = in + (size_t)e * R * C;
  ushort_t* dst = out + (size_t)e * R * C;
  const int c0 = blockIdx.x * 32, r0 = blockIdx.y * 32;
  const int tx = threadIdx.x, ty = threadIdx.y;
#pragma unroll
  for (int j = 0; j < 32; j += 8)
    tile[ty + j][tx] = src[(size_t)(r0 + ty + j) * C + c0 + tx];
  __syncthreads();
#pragma unroll
  for (int j = 0; j < 32; j += 8)
    dst[(size_t)(c0 + ty + j) * R + r0 + tx] = f2bf(tile[tx][ty + j]);
}

// ======== 256x256 / BK=64 / 2-set, 8-phase quadrant GEMM (m201 reconstruction) ========
// Set s (64KB): A[256 rows][64 k] @ s*65536 (pitch 128B), B[256 n][64 k] @ +32768.
// Swizzle: LDS granule slot holds global granule slot ^ (row&7)  (2-way = free).
// Group of 4 phases consumes one set; phase 0 reads all B (held in regs) + batch-stages
// the OTHER set (8 gl_lds16/thread); single vmcnt(0) at group end joins a batch issued
// ~3.5 phases (~1700 cy) earlier.

template <int Q>
__device__ __forceinline__ void mfma_phase(const bf16x8& a00, const bf16x8& a01,
                                           const bf16x8& a10, const bf16x8& a11,
                                           bf16x8 (&b0)[4], bf16x8 (&b1)[4],
                                           f32x4 (&acc)[8][4]) {
  __builtin_amdgcn_s_setprio(1);
#pragma unroll
  for (int n = 0; n < 4; n++) acc[2*Q+0][n] = MFMA(a00, b0[n], acc[2*Q+0][n]);
#pragma unroll
  for (int n = 0; n < 4; n++) acc[2*Q+1][n] = MFMA(a01, b0[n], acc[2*Q+1][n]);
#pragma unroll
  for (int n = 0; n < 4; n++) acc[2*Q+0][n] = MFMA(a10, b1[n], acc[2*Q+0][n]);
#pragma unroll
  for (int n = 0; n < 4; n++) acc[2*Q+1][n] = MFMA(a11, b1[n], acc[2*Q+1][n]);
  __builtin_amdgcn_s_setprio(0);
}

template <bool STG, int LDA>
__device__ __forceinline__ void group4(unsigned aG0, unsigned aG1,
                                       unsigned bG0, unsigned bG1,
                                       const ushort_t* sA, const ushort_t* sB,
                                       int kt, char* dstSet, int wave,
                                       f32x4 (&acc)[8][4]) {
  bf16x8 b0[4], b1[4], a00, a01, a10, a11;
  // ---- phase 0: all B + A-quad0 reads; batch-stage other set ----
  DS_READ(b0[0], bG0, "0");    DS_READ(b0[1], bG0, "2048");
  DS_READ(b0[2], bG0, "4096"); DS_READ(b0[3], bG0, "6144");
  DS_READ(b1[0], bG1, "0");    DS_READ(b1[1], bG1, "2048");
  DS_READ(b1[2], bG1, "4096"); DS_READ(b1[3], bG1, "6144");
  DS_READ(a00, aG0, "0");      DS_READ(a01, aG0, "2048");
  DS_READ(a10, aG1, "0");      DS_READ(a11, aG1, "2048");
  if (STG) {
    char* dA = dstSet + wave * 1024;
    char* dB = dstSet + 32768 + wave * 1024;
#pragma unroll
    for (int c2 = 0; c2 < 4; ++c2)
      gl_lds16(sA + (size_t)c2 * 64 * LDA + kt, dA + c2 * 8192);
#pragma unroll
    for (int c2 = 0; c2 < 4; ++c2)
      gl_lds16(sB + (size_t)c2 * 64 * LDA + kt, dB + c2 * 8192);
  }
  SCHED0; BAR; WAITL0; SCHED0;
  mfma_phase<0>(a00, a01, a10, a11, b0, b1, acc);
  SCHED0; BAR;
  // ---- phase 1 ----
  DS_READ(a00, aG0, "4096"); DS_READ(a01, aG0, "6144");
  DS_READ(a10, aG1, "4096"); DS_READ(a11, aG1, "6144");
  SCHED0; BAR; WAITL0; SCHED0;
  mfma_phase<1>(a00, a01, a10, a11, b0, b1, acc);
  SCHED0; BAR;
  // ---- phase 2 ----
  DS_READ(a00, aG0, "8192"); DS_READ(a01, aG0, "10240");
  DS_READ(a10, aG1, "8192"); DS_READ(a11, aG1, "10240");
  SCHED0; BAR; WAITL0; SCHED0;
  mfma_phase<2>(a00, a01, a10, a11, b0, b1, acc);
  SCHED0; BAR;
  // ---- phase 3 + group-end join ----
  DS_READ(a00, aG0, "12288"); DS_READ(a01, aG0, "14336");
  DS_READ(a10, aG1, "12288"); DS_READ(a11, aG1, "14336");
  SCHED0; BAR; WAITL0; SCHED0;
  mfma_phase<3>(a00, a01, a10, a11, b0, b1, acc);
  SCHED0; WAITV0; BAR; SCHED0;
}

// EPI=0: H = gelu(A@B + bias), bf16. EPI=1: O = resid + A@B + bias, f32.
template <int EPI, int LDA, int LDC, int KTOT>
__global__ __launch_bounds__(512, 2) void gemm256(const ushort_t* __restrict__ A,
                                                  const ushort_t* __restrict__ Bw,
                                                  const float* __restrict__ bias,
                                                  const float* __restrict__ resid,
                                                  ushort_t* __restrict__ Hout,
                                                  float* __restrict__ Fout) {
  extern __shared__ char smem[];
  const int tid = threadIdx.x;
  const int wave = tid >> 6, lane = tid & 63;

  const int bid = blockIdx.x;
  const int c = bid & 7, l = bid >> 3;
  const int tm = c * 8 + (l & 7);
  const int tn = l >> 3;
  const int row0 = tm * 256;
  const int col0 = tn * 256;
  const int e = (row0 >> 9) & 7;

  const ushort_t* gA = A + (size_t)row0 * LDA;
  const ushort_t* gB = Bw + ((size_t)e * LDC + col0) * LDA;

  const int NI = KTOT / 128;   // iterations (2 K-tiles each)

  const int wm = wave >> 2, wn = wave & 3;
  const int l15 = lane & 15, g = lane >> 4, l7 = lane & 7;

  // fragment read bases: row pitch 128B; granule slot = gk ^ (row&7), row&7 = lane&7
  const unsigned lds0 = lds_addr(smem);
  const unsigned g0 = ((unsigned)((g     ) ^ l7)) << 4;
  const unsigned g1 = ((unsigned)((g + 4 ) ^ l7)) << 4;
  const unsigned aS0g0 = lds0 + (wm * 128 + l15) * 128 + g0;
  const unsigned aS0g1 = lds0 + (wm * 128 + l15) * 128 + g1;
  const unsigned bS0g0 = lds0 + 32768 + (wn * 64 + l15) * 128 + g0;
  const unsigned bS0g1 = lds0 + 32768 + (wn * 64 + l15) * 128 + g1;
  const unsigned aS1g0 = aS0g0 + 65536, aS1g1 = aS0g1 + 65536;
  const unsigned bS1g0 = bS0g0 + 65536, bS1g1 = bS0g1 + 65536;

  // staging source: dest row = 64c + tid>>3, dest granule = tid&7 (linear dest);
  // source granule = dest ^ (row&7)
  const int sgr = (tid & 7) ^ ((tid >> 3) & 7);
  const ushort_t* sA = gA + (size_t)(tid >> 3) * LDA + sgr * 8;
  const ushort_t* sB = gB + (size_t)(tid >> 3) * LDA + sgr * 8;

  f32x4 acc[8][4] = {};

  // prologue: batch-stage set0 <- K-tile 0
  {
    char* dA = smem + wave * 1024;
    char* dB = smem + 32768 + wave * 1024;
#pragma unroll
    for (int c2 = 0; c2 < 4; ++c2)
      gl_lds16(sA + (size_t)c2 * 64 * LDA, dA + c2 * 8192);
#pragma unroll
    for (int c2 = 0; c2 < 4; ++c2)
      gl_lds16(sB + (size_t)c2 * 64 * LDA, dB + c2 * 8192);
  }
  WAITV0; BAR; SCHED0;

  // steady: group1 computes set0 (tile 2i), stages set1 <- tile 2i+1 (joined at group end);
  //         group2 computes set1 (tile 2i+1), stages set0 <- tile 2i+2.
#pragma unroll 1
  for (int i = 0; i < NI - 1; ++i) {
    group4<true, LDA>(aS0g0, aS0g1, bS0g0, bS0g1, sA, sB, (2*i+1)*64, smem + 65536, wave, acc);
    group4<true, LDA>(aS1g0, aS1g1, bS1g0, bS1g1, sA, sB, (2*i+2)*64, smem,         wave, acc);
  }
  group4<true,  LDA>(aS0g0, aS0g1, bS0g0, bS0g1, sA, sB, (2*NI-1)*64, smem + 65536, wave, acc);
  group4<false, LDA>(aS1g0, aS1g1, bS1g0, bS1g1, sA, sB, 0,           smem,         wave, acc);

  // ---------------- LDS-gather epilogue: 4 rounds x 64 rows ----------------
  __syncthreads();

  float bv[4];
#pragma unroll
  for (int ni = 0; ni < 4; ni++)
    bv[ni] = bias[e * LDC + col0 + wn * 64 + ni * 16 + l15];

#pragma unroll
  for (int r = 0; r < 4; ++r) {
#pragma unroll
    for (int mh = 0; mh < 2; ++mh) {
      const int mi = 2 * r + mh;
      const int lrow = wm * 32 + mh * 16 + g * 4;
#pragma unroll
      for (int ni = 0; ni < 4; ++ni) {
        const int colb = (wn * 64 + ni * 16 + l15) * 4;
#pragma unroll
        for (int rr = 0; rr < 4; ++rr) {
          float v = acc[mi][ni][rr] + bv[ni];
          if (EPI == 0) {
            float v2 = v * v;
            float cc = fmaf(0.044715f, v2, 1.0f);
            float u  = exp2f(-2.3022078f * v * cc);
            v = __fdividef(v, 1.0f + u);
          }
          *(float*)(smem + (size_t)(lrow + rr) * EPI_STRIDE + colb) = v;
        }
      }
    }
    __syncthreads();
#pragma unroll
    for (int i = 0; i < 8; ++i) {
      const int chunk = i * 512 + tid;
      const int lr = chunk >> 6;
      const int cb = (chunk & 63) * 16;
      const float4 v4 = *(const float4*)(smem + (size_t)lr * EPI_STRIDE + cb);
      const int grow = row0 + (lr < 32 ? r * 32 + lr : 128 + r * 32 + (lr - 32));
      const int gcol = col0 + (chunk & 63) * 4;
      if (EPI == 0) {
        ushort4 o;
        o.x = f2bf(v4.x); o.y = f2bf(v4.y); o.z = f2bf(v4.z); o.w = f2bf(v4.w);
        *(ushort4*)(&Hout[(size_t)grow * LDC + gcol]) = o;
      } else {
        const float4 rs = *(const float4*)(&resid[(size_t)grow * LDC + gcol]);
        float4 o;
        o.x = v4.x + rs.x; o.y = v4.y + rs.y; o.z = v4.z + rs.z; o.w = v4.w + rs.w;
        *(float4*)(&Fout[(size_t)grow * LDC + gcol]) = o;
      }
    }
    __syncthreads();
  }
}

extern "C" void kernel_launch(void* const* d_in, const int* in_sizes, int n_in,
                              void* d_out, int out_size, void* d_ws, size_t ws_size,
                              hipStream_t stream) {
  const float* x     = (const float*)d_in[0];
  const float* gamma = (const float*)d_in[1];
  const float* beta  = (const float*)d_in[2];
  // d_in[3] = gate_w : logits discarded by the reference -> skip
  const float* w1    = (const float*)d_in[4];
  const float* b1    = (const float*)d_in[5];
  const float* w2    = (const float*)d_in[6];
  const float* b2    = (const float*)d_in[7];
  float* out = (float*)d_out;

  char* ws = (char*)d_ws;
  ushort_t* xn  = (ushort_t*)ws;                                   // 32MB
  ushort_t* w1t = (ushort_t*)(ws + 33554432);                      // 64MB
  ushort_t* w2t = (ushort_t*)(ws + 33554432 + 67108864);           // 64MB
  ushort_t* h   = (ushort_t*)(ws + 33554432 + 2 * 67108864);       // 128MB

  hipFuncSetAttribute(reinterpret_cast<const void*>(&gemm256<0, 1024, 4096, 1024>),
                      hipFuncAttributeMaxDynamicSharedMemorySize, 131072);
  hipFuncSetAttribute(reinterpret_cast<const void*>(&gemm256<1, 4096, 1024, 4096>),
                      hipFuncAttributeMaxDynamicSharedMemorySize, 131072);

  ln_kernel<<<16384, 256, 0, stream>>>(x, gamma, beta, xn);
  transpose_cast<<<dim3(128, 32, 8), dim3(32, 8), 0, stream>>>(w1, w1t, 1024, 4096);
  transpose_cast<<<dim3(32, 128, 8), dim3(32, 8), 0, stream>>>(w2, w2t, 4096, 1024);

  // GEMM1: M=16384 N=4096 K=1024 -> h = gelu(xn@w1 + b1)
  gemm256<0, 1024, 4096, 1024><<<dim3(1024), 512, 131072, stream>>>(xn, w1t, b1, nullptr, h, nullptr);
  // GEMM2: M=16384 N=1024 K=4096 -> out = x + h@w2 + b2
  gemm256<1, 4096, 1024, 4096><<<dim3(256), 512, 131072, stream>>>(h, w2t, b2, x, nullptr, out);
}